// Round 1
// baseline (1525.635 us; speedup 1.0000x reference)
//
#include <hip/hip_runtime.h>

#define BB 8
#define CC 512
#define NSP 1024
#define HEADS 8
#define DH 64
#define NGROUPS 32
#define CPG 16
#define GN_EPS 1e-5f
#define TQ 8

__device__ __forceinline__ float wave_reduce_sum(float v) {
    #pragma unroll
    for (int off = 32; off > 0; off >>= 1) v += __shfl_down(v, off, 64);
    return v;
}
__device__ __forceinline__ float wave_reduce_max(float v) {
    #pragma unroll
    for (int off = 32; off > 0; off >>= 1) v = fmaxf(v, __shfl_down(v, off, 64));
    return v;
}

// ---------------- GroupNorm: one block per (b, group) ----------------
__global__ __launch_bounds__(256) void groupnorm_kernel(
        const float* __restrict__ x, const float* __restrict__ gsc,
        const float* __restrict__ gbi, float* __restrict__ hn) {
    const int b = blockIdx.x / NGROUPS, g = blockIdx.x % NGROUPS;
    const int count = CPG * NSP;  // 16384
    const size_t base = ((size_t)b * CC + (size_t)g * CPG) * NSP;
    float s = 0.f, ss = 0.f;
    for (int i = threadIdx.x; i < count; i += 256) {
        float v = x[base + i];
        s += v; ss += v * v;
    }
    __shared__ float red[2][4];
    s = wave_reduce_sum(s); ss = wave_reduce_sum(ss);
    const int wid = threadIdx.x >> 6, lane = threadIdx.x & 63;
    if (lane == 0) { red[0][wid] = s; red[1][wid] = ss; }
    __syncthreads();
    if (threadIdx.x == 0) {
        float ts  = red[0][0] + red[0][1] + red[0][2] + red[0][3];
        float tss = red[1][0] + red[1][1] + red[1][2] + red[1][3];
        float mu = ts / count;
        float var = tss / count - mu * mu;
        red[0][0] = mu;
        red[1][0] = rsqrtf(var + GN_EPS);
    }
    __syncthreads();
    const float mu = red[0][0], rstd = red[1][0];
    for (int i = threadIdx.x; i < count; i += 256) {
        int c = g * CPG + (i >> 10);
        hn[base + i] = (x[base + i] - mu) * rstd * gsc[c] + gbi[c];
    }
}

// ---------------- fp32 tiled GEMM: Y[b,o,n] = bias[o] + sum_c W[o,c] X[b,c,n] (+res) ----
__global__ __launch_bounds__(256) void gemm512_kernel(
        const float* __restrict__ W, const float* __restrict__ bias,
        const float* __restrict__ X, float* __restrict__ Y,
        const float* __restrict__ res) {
    __shared__ float Ws[64][68];
    __shared__ float Xs[64][68];
    const int n0 = blockIdx.x * 64, o0 = blockIdx.y * 64, b = blockIdx.z;
    const int t = threadIdx.x;
    const int tx = t & 15, ty = t >> 4;
    float acc[4][4] = {};
    for (int c0 = 0; c0 < CC; c0 += 64) {
        for (int i = t; i < 4096; i += 256) {
            int r = i >> 6, cc = i & 63;
            Ws[r][cc] = W[(size_t)(o0 + r) * CC + c0 + cc];
            Xs[r][cc] = X[((size_t)b * CC + c0 + r) * NSP + n0 + cc];
        }
        __syncthreads();
        #pragma unroll 8
        for (int cc = 0; cc < 64; ++cc) {
            float a0 = Ws[ty * 4 + 0][cc], a1 = Ws[ty * 4 + 1][cc];
            float a2 = Ws[ty * 4 + 2][cc], a3 = Ws[ty * 4 + 3][cc];
            float x0 = Xs[cc][tx * 4 + 0], x1 = Xs[cc][tx * 4 + 1];
            float x2 = Xs[cc][tx * 4 + 2], x3 = Xs[cc][tx * 4 + 3];
            acc[0][0] += a0 * x0; acc[0][1] += a0 * x1; acc[0][2] += a0 * x2; acc[0][3] += a0 * x3;
            acc[1][0] += a1 * x0; acc[1][1] += a1 * x1; acc[1][2] += a1 * x2; acc[1][3] += a1 * x3;
            acc[2][0] += a2 * x0; acc[2][1] += a2 * x1; acc[2][2] += a2 * x2; acc[2][3] += a2 * x3;
            acc[3][0] += a3 * x0; acc[3][1] += a3 * x1; acc[3][2] += a3 * x2; acc[3][3] += a3 * x3;
        }
        __syncthreads();
    }
    #pragma unroll
    for (int i = 0; i < 4; ++i) {
        const int o = o0 + ty * 4 + i;
        const float bv = bias[o];
        const size_t rowbase = ((size_t)b * CC + o) * NSP + n0 + tx * 4;
        #pragma unroll
        for (int j = 0; j < 4; ++j) {
            float v = acc[i][j] + bv;
            if (res) v += res[rowbase + j];
            Y[rowbase + j] = v;
        }
    }
}

// ---------------- attention: one block per (b, h, q-tile of 8) ----------------
__global__ __launch_bounds__(256) void attn_kernel(
        const float* __restrict__ qbuf, const float* __restrict__ kbuf,
        const float* __restrict__ vbuf, float* __restrict__ obuf) {
    __shared__ float S[TQ][NSP];    // 32 KB
    __shared__ float Vs[64][68];    // 17 KB
    __shared__ float Qs[TQ][64];    // 2 KB
    __shared__ float Os[64][TQ];    // 2 KB
    const int q0 = blockIdx.x * TQ;
    const int h = blockIdx.y, b = blockIdx.z;
    const int t = threadIdx.x;
    const size_t headbase = ((size_t)b * CC + (size_t)h * DH) * NSP;

    // load Q tile -> Qs[q][d]
    for (int i = t; i < TQ * 64; i += 256) {
        int q = i & (TQ - 1), d = i >> 3;
        Qs[q][d] = qbuf[headbase + (size_t)d * NSP + q0 + q];
    }
    __syncthreads();

    // scores: S[q][k] = scale * sum_d Q[q][d] K[d][k]
    const float scale = 0.125f;  // 1/sqrt(64)
    for (int k0 = 0; k0 < NSP; k0 += 256) {
        const int kk = k0 + t;
        float acc[TQ] = {};
        for (int d = 0; d < 64; ++d) {
            float kv = kbuf[headbase + (size_t)d * NSP + kk];
            #pragma unroll
            for (int q = 0; q < TQ; ++q) acc[q] += Qs[q][d] * kv;
        }
        #pragma unroll
        for (int q = 0; q < TQ; ++q) S[q][kk] = acc[q] * scale;
    }
    __syncthreads();

    // softmax: wave w owns rows 2w, 2w+1
    const int wid = t >> 6, lane = t & 63;
    for (int r = wid * 2; r < wid * 2 + 2; ++r) {
        float m = -1e30f;
        for (int j = lane; j < NSP; j += 64) m = fmaxf(m, S[r][j]);
        m = wave_reduce_max(m);
        m = __shfl(m, 0, 64);
        float sum = 0.f;
        for (int j = lane; j < NSP; j += 64) {
            float e = __expf(S[r][j] - m);
            S[r][j] = e;
            sum += e;
        }
        sum = wave_reduce_sum(sum);
        sum = __shfl(sum, 0, 64);
        const float inv = 1.0f / sum;
        for (int j = lane; j < NSP; j += 64) S[r][j] *= inv;
    }
    __syncthreads();

    // O[d][q] = sum_k P[q][k] V[d][k]
    const int d = t & 63;
    const int w = t >> 6;
    const int qa = w * 2, qc = w * 2 + 1;
    float oa = 0.f, oc = 0.f;
    for (int k0 = 0; k0 < NSP; k0 += 64) {
        for (int i = t; i < 4096; i += 256) {
            int dd = i >> 6, kv = i & 63;
            Vs[dd][kv] = vbuf[headbase + (size_t)dd * NSP + k0 + kv];
        }
        __syncthreads();
        #pragma unroll 16
        for (int kv = 0; kv < 64; ++kv) {
            float v = Vs[d][kv];
            oa += S[qa][k0 + kv] * v;
            oc += S[qc][k0 + kv] * v;
        }
        __syncthreads();
    }
    Os[d][qa] = oa;
    Os[d][qc] = oc;
    __syncthreads();
    for (int i = t; i < 64 * TQ; i += 256) {
        int dd = i >> 3, q = i & (TQ - 1);
        obuf[headbase + (size_t)dd * NSP + q0 + q] = Os[dd][q];
    }
}

extern "C" void kernel_launch(void* const* d_in, const int* in_sizes, int n_in,
                              void* d_out, int out_size, void* d_ws, size_t ws_size,
                              hipStream_t stream) {
    const float* x   = (const float*)d_in[0];
    const float* gsc = (const float*)d_in[1];
    const float* gbi = (const float*)d_in[2];
    const float* wq  = (const float*)d_in[3];
    const float* bq  = (const float*)d_in[4];
    const float* wk  = (const float*)d_in[5];
    const float* bk  = (const float*)d_in[6];
    const float* wv  = (const float*)d_in[7];
    const float* bv  = (const float*)d_in[8];
    const float* wo  = (const float*)d_in[9];
    const float* bo  = (const float*)d_in[10];
    float* out = (float*)d_out;

    const size_t SZ = (size_t)BB * CC * NSP;  // 4.19M floats
    float* hn   = (float*)d_ws;
    float* qb   = hn + SZ;
    float* kb   = qb + SZ;
    float* vb   = kb + SZ;
    float* ohb  = vb + SZ;

    groupnorm_kernel<<<BB * NGROUPS, 256, 0, stream>>>(x, gsc, gbi, hn);

    dim3 ggrid(NSP / 64, CC / 64, BB);
    gemm512_kernel<<<ggrid, 256, 0, stream>>>(wq, bq, hn, qb, nullptr);
    gemm512_kernel<<<ggrid, 256, 0, stream>>>(wk, bk, hn, kb, nullptr);
    gemm512_kernel<<<ggrid, 256, 0, stream>>>(wv, bv, hn, vb, nullptr);

    dim3 agrid(NSP / TQ, HEADS, BB);
    attn_kernel<<<agrid, 256, 0, stream>>>(qb, kb, vb, ohb);

    gemm512_kernel<<<ggrid, 256, 0, stream>>>(wo, bo, ohb, out, x);
}

// Round 2
// 427.908 us; speedup vs baseline: 3.5653x; 3.5653x over previous
//
#include <hip/hip_runtime.h>

#define BB 8
#define CC 512
#define NSP 1024
#define HEADS 8
#define DH 64
#define NGROUPS 32
#define CPG 16
#define GN_EPS 1e-5f

typedef __attribute__((ext_vector_type(8))) short bf16x8;
typedef __attribute__((ext_vector_type(4))) short short4v;
typedef __attribute__((ext_vector_type(4))) float f32x4;

__device__ __forceinline__ short f2bf(float f) {
    union { float f; unsigned u; } v; v.f = f;
    unsigned r = v.u + 0x7fffu + ((v.u >> 16) & 1u);
    return (short)(r >> 16);
}

__device__ __forceinline__ float wave_reduce_sum(float v) {
    #pragma unroll
    for (int off = 32; off > 0; off >>= 1) v += __shfl_down(v, off, 64);
    return v;
}

// ---------------- GroupNorm: one block per (b, group) ----------------
__global__ __launch_bounds__(256) void groupnorm_kernel(
        const float* __restrict__ x, const float* __restrict__ gsc,
        const float* __restrict__ gbi, float* __restrict__ hn) {
    const int b = blockIdx.x / NGROUPS, g = blockIdx.x % NGROUPS;
    const int count = CPG * NSP;  // 16384
    const size_t base = ((size_t)b * CC + (size_t)g * CPG) * NSP;
    float s = 0.f, ss = 0.f;
    for (int i = threadIdx.x; i < count; i += 256) {
        float v = x[base + i];
        s += v; ss += v * v;
    }
    __shared__ float red[2][4];
    s = wave_reduce_sum(s); ss = wave_reduce_sum(ss);
    const int wid = threadIdx.x >> 6, lane = threadIdx.x & 63;
    if (lane == 0) { red[0][wid] = s; red[1][wid] = ss; }
    __syncthreads();
    if (threadIdx.x == 0) {
        float ts  = red[0][0] + red[0][1] + red[0][2] + red[0][3];
        float tss = red[1][0] + red[1][1] + red[1][2] + red[1][3];
        float mu = ts / count;
        float var = tss / count - mu * mu;
        red[0][0] = mu;
        red[1][0] = rsqrtf(var + GN_EPS);
    }
    __syncthreads();
    const float mu = red[0][0], rstd = red[1][0];
    for (int i = threadIdx.x; i < count; i += 256) {
        int c = g * CPG + (i >> 10);
        hn[base + i] = (x[base + i] - mu) * rstd * gsc[c] + gbi[c];
    }
}

// ---------------- fp32 tiled GEMM: Y[b,o,n] = bias[o] + sum_c W[o,c] X[b,c,n] (+res) ----
__global__ __launch_bounds__(256) void gemm512_kernel(
        const float* __restrict__ W, const float* __restrict__ bias,
        const float* __restrict__ X, float* __restrict__ Y,
        const float* __restrict__ res) {
    __shared__ float Ws[64][68];
    __shared__ float Xs[64][68];
    const int n0 = blockIdx.x * 64, o0 = blockIdx.y * 64, b = blockIdx.z;
    const int t = threadIdx.x;
    const int tx = t & 15, ty = t >> 4;
    float acc[4][4] = {};
    for (int c0 = 0; c0 < CC; c0 += 64) {
        for (int i = t; i < 4096; i += 256) {
            int r = i >> 6, cc = i & 63;
            Ws[r][cc] = W[(size_t)(o0 + r) * CC + c0 + cc];
            Xs[r][cc] = X[((size_t)b * CC + c0 + r) * NSP + n0 + cc];
        }
        __syncthreads();
        #pragma unroll 8
        for (int cc = 0; cc < 64; ++cc) {
            float a0 = Ws[ty * 4 + 0][cc], a1 = Ws[ty * 4 + 1][cc];
            float a2 = Ws[ty * 4 + 2][cc], a3 = Ws[ty * 4 + 3][cc];
            float x0 = Xs[cc][tx * 4 + 0], x1 = Xs[cc][tx * 4 + 1];
            float x2 = Xs[cc][tx * 4 + 2], x3 = Xs[cc][tx * 4 + 3];
            acc[0][0] += a0 * x0; acc[0][1] += a0 * x1; acc[0][2] += a0 * x2; acc[0][3] += a0 * x3;
            acc[1][0] += a1 * x0; acc[1][1] += a1 * x1; acc[1][2] += a1 * x2; acc[1][3] += a1 * x3;
            acc[2][0] += a2 * x0; acc[2][1] += a2 * x1; acc[2][2] += a2 * x2; acc[2][3] += a2 * x3;
            acc[3][0] += a3 * x0; acc[3][1] += a3 * x1; acc[3][2] += a3 * x2; acc[3][3] += a3 * x3;
        }
        __syncthreads();
    }
    #pragma unroll
    for (int i = 0; i < 4; ++i) {
        const int o = o0 + ty * 4 + i;
        const float bv = bias[o];
        const size_t rowbase = ((size_t)b * CC + o) * NSP + n0 + tx * 4;
        #pragma unroll
        for (int j = 0; j < 4; ++j) {
            float v = acc[i][j] + bv;
            if (res) v += res[rowbase + j];
            Y[rowbase + j] = v;
        }
    }
}

// ---------------- flash attention, MFMA bf16 ----------------
// block: 256 threads = 4 waves; each wave owns 16 queries of a 64-query tile.
// grid: (N/64, HEADS, B). K-loop over 16 tiles of 64 keys.
__global__ __launch_bounds__(256) void attn_mfma_kernel(
        const float* __restrict__ qbuf, const float* __restrict__ kbuf,
        const float* __restrict__ vbuf, float* __restrict__ obuf) {
    __shared__ short Ks[64][72];      // [key][d]  (K^T tile)  9216 B, 144 B rows
    __shared__ short Vs[64][72];      // [d][key]               9216 B
    __shared__ short Ps[4][16][72];   // per-wave [q][key]      9216 B
    const int q0 = blockIdx.x * 64;
    const int h = blockIdx.y, b = blockIdx.z;
    const int t = threadIdx.x;
    const int w = t >> 6, lane = t & 63;
    const int quad = lane >> 4, l16 = lane & 15;
    const size_t headbase = ((size_t)b * CC + (size_t)h * DH) * NSP;
    const int qcol = q0 + w * 16 + l16;

    // Q fragments (B-operand layout: B[kdim=d][n=q], d = quad*8 + j + 32*s)
    bf16x8 qf[2];
    #pragma unroll
    for (int s = 0; s < 2; ++s) {
        short tmp[8];
        #pragma unroll
        for (int j = 0; j < 8; ++j) {
            int d = quad * 8 + j + 32 * s;
            tmp[j] = f2bf(qbuf[headbase + (size_t)d * NSP + qcol]);
        }
        qf[s] = *(bf16x8*)tmp;
    }

    float mrun = -1e30f, lrun = 0.f;
    f32x4 oacc[4];
    #pragma unroll
    for (int i = 0; i < 4; ++i) oacc[i] = (f32x4){0.f, 0.f, 0.f, 0.f};
    const float scale = 0.125f;  // 1/sqrt(64)

    for (int k0 = 0; k0 < NSP; k0 += 64) {
        __syncthreads();
        // ---- stage K^T tile: Ks[k][d], each thread packs 8 d's for one k (b128 write)
        #pragma unroll
        for (int p = 0; p < 2; ++p) {
            int idx = t + p * 256;            // 0..511
            int k = idx & 63, d8 = (idx >> 6) * 8;
            const float* src = kbuf + headbase + (size_t)d8 * NSP + k0 + k;
            short tmp[8];
            #pragma unroll
            for (int j = 0; j < 8; ++j) tmp[j] = f2bf(src[(size_t)j * NSP]);
            *(bf16x8*)&Ks[k][d8] = *(bf16x8*)tmp;
        }
        // ---- stage V tile: Vs[d][k], thread packs 8 consecutive k (b128 write)
        #pragma unroll
        for (int p = 0; p < 2; ++p) {
            int idx = t + p * 256;            // 0..511
            int d = idx >> 3, k8 = (idx & 7) * 8;
            const float* src = vbuf + headbase + (size_t)d * NSP + k0 + k8;
            float4 a = *(const float4*)src;
            float4 c = *(const float4*)(src + 4);
            short tmp[8] = { f2bf(a.x), f2bf(a.y), f2bf(a.z), f2bf(a.w),
                             f2bf(c.x), f2bf(c.y), f2bf(c.z), f2bf(c.w) };
            *(bf16x8*)&Vs[d][k8] = *(bf16x8*)tmp;
        }
        __syncthreads();

        // ---- S^T = K^T Q : 4 frags of [16 keys x 16 q]
        f32x4 st[4];
        #pragma unroll
        for (int ks = 0; ks < 4; ++ks) {
            f32x4 acc = (f32x4){0.f, 0.f, 0.f, 0.f};
            #pragma unroll
            for (int s = 0; s < 2; ++s) {
                bf16x8 ka = *(bf16x8*)&Ks[ks * 16 + l16][quad * 8 + 32 * s];
                acc = __builtin_amdgcn_mfma_f32_16x16x32_bf16(ka, qf[s], acc, 0, 0, 0);
            }
            st[ks] = acc;
        }
        // ---- online softmax over this tile's 64 keys (per query col = l16)
        float tmax = -1e30f;
        #pragma unroll
        for (int ks = 0; ks < 4; ++ks)
            #pragma unroll
            for (int r = 0; r < 4; ++r) {
                st[ks][r] *= scale;
                tmax = fmaxf(tmax, st[ks][r]);
            }
        tmax = fmaxf(tmax, __shfl_xor(tmax, 16, 64));
        tmax = fmaxf(tmax, __shfl_xor(tmax, 32, 64));
        float mnew = fmaxf(mrun, tmax);
        float alpha = __expf(mrun - mnew);
        float psum = 0.f;
        short pb[16];
        #pragma unroll
        for (int ks = 0; ks < 4; ++ks)
            #pragma unroll
            for (int r = 0; r < 4; ++r) {
                float p = __expf(st[ks][r] - mnew);
                psum += p;
                pb[ks * 4 + r] = f2bf(p);
            }
        psum += __shfl_xor(psum, 16, 64);
        psum += __shfl_xor(psum, 32, 64);
        lrun = lrun * alpha + psum;
        mrun = mnew;
        #pragma unroll
        for (int i = 0; i < 4; ++i)
            #pragma unroll
            for (int r = 0; r < 4; ++r) oacc[i][r] *= alpha;

        // ---- P round-trip through per-wave LDS (keys row-major per query)
        #pragma unroll
        for (int ks = 0; ks < 4; ++ks)
            *(short4v*)&Ps[w][l16][ks * 16 + quad * 4] = *(short4v*)&pb[ks * 4];
        bf16x8 pf[2];
        #pragma unroll
        for (int s = 0; s < 2; ++s)
            pf[s] = *(bf16x8*)&Ps[w][l16][quad * 8 + 32 * s];

        // ---- O += V P^T : A = Vs[m=d][k=key], B = pf
        #pragma unroll
        for (int ds = 0; ds < 4; ++ds)
            #pragma unroll
            for (int s = 0; s < 2; ++s) {
                bf16x8 va = *(bf16x8*)&Vs[ds * 16 + l16][quad * 8 + 32 * s];
                oacc[ds] = __builtin_amdgcn_mfma_f32_16x16x32_bf16(va, pf[s], oacc[ds], 0, 0, 0);
            }
    }

    // ---- epilogue: divide by l, store. row d = ds*16 + quad*4 + r, col = qcol
    const float inv = 1.0f / lrun;
    #pragma unroll
    for (int ds = 0; ds < 4; ++ds)
        #pragma unroll
        for (int r = 0; r < 4; ++r) {
            int d = ds * 16 + quad * 4 + r;
            obuf[headbase + (size_t)d * NSP + qcol] = oacc[ds][r] * inv;
        }
}

extern "C" void kernel_launch(void* const* d_in, const int* in_sizes, int n_in,
                              void* d_out, int out_size, void* d_ws, size_t ws_size,
                              hipStream_t stream) {
    const float* x   = (const float*)d_in[0];
    const float* gsc = (const float*)d_in[1];
    const float* gbi = (const float*)d_in[2];
    const float* wq  = (const float*)d_in[3];
    const float* bq  = (const float*)d_in[4];
    const float* wk  = (const float*)d_in[5];
    const float* bk  = (const float*)d_in[6];
    const float* wv  = (const float*)d_in[7];
    const float* bv  = (const float*)d_in[8];
    const float* wo  = (const float*)d_in[9];
    const float* bo  = (const float*)d_in[10];
    float* out = (float*)d_out;

    const size_t SZ = (size_t)BB * CC * NSP;  // 4.19M floats
    float* hn   = (float*)d_ws;
    float* qb   = hn + SZ;
    float* kb   = qb + SZ;
    float* vb   = kb + SZ;
    float* ohb  = vb + SZ;

    groupnorm_kernel<<<BB * NGROUPS, 256, 0, stream>>>(x, gsc, gbi, hn);

    dim3 ggrid(NSP / 64, CC / 64, BB);
    gemm512_kernel<<<ggrid, 256, 0, stream>>>(wq, bq, hn, qb, nullptr);
    gemm512_kernel<<<ggrid, 256, 0, stream>>>(wk, bk, hn, kb, nullptr);
    gemm512_kernel<<<ggrid, 256, 0, stream>>>(wv, bv, hn, vb, nullptr);

    dim3 agrid(NSP / 64, HEADS, BB);
    attn_mfma_kernel<<<agrid, 256, 0, stream>>>(qb, kb, vb, ohb);

    gemm512_kernel<<<ggrid, 256, 0, stream>>>(wo, bo, ohb, out, x);
}

// Round 3
// 201.276 us; speedup vs baseline: 7.5798x; 2.1260x over previous
//
#include <hip/hip_runtime.h>

#define BB 8
#define CC 512
#define NSP 1024
#define HEADS 8
#define DH 64
#define NGROUPS 32
#define CPG 16
#define GN_EPS 1e-5f
#define MQKV 1536

typedef __attribute__((ext_vector_type(8))) short bf16x8;
typedef __attribute__((ext_vector_type(4))) short short4v;
typedef __attribute__((ext_vector_type(4))) float f32x4;

typedef __attribute__((address_space(3))) unsigned int lds_u32;
typedef const __attribute__((address_space(1))) unsigned int glb_u32;

__device__ __forceinline__ short f2bf(float f) {
    union { float f; unsigned u; } v; v.f = f;
    unsigned r = v.u + 0x7fffu + ((v.u >> 16) & 1u);
    return (short)(r >> 16);
}

__device__ __forceinline__ float wave_reduce_sum(float v) {
    #pragma unroll
    for (int off = 32; off > 0; off >>= 1) v += __shfl_down(v, off, 64);
    return v;
}

// ---------------- weight convert: wq/wk/wv -> wqkv bf16 [1536][512], wo -> bf16 ----
__global__ __launch_bounds__(256) void convert_w_kernel(
        const float* __restrict__ wq, const float* __restrict__ wk,
        const float* __restrict__ wv, const float* __restrict__ wo,
        const float* __restrict__ bq, const float* __restrict__ bk,
        const float* __restrict__ bv,
        short* __restrict__ wqkv, short* __restrict__ wob,
        float* __restrict__ bqkv) {
    const int gid = blockIdx.x * 256 + threadIdx.x;
    if (gid < MQKV * CC) {
        const int r = gid >> 9;
        const int cc = gid & 511;
        const float* src = (r < 512) ? wq : ((r < 1024) ? wk : wv);
        wqkv[gid] = f2bf(src[(size_t)(r & 511) * CC + cc]);
    } else {
        const int g2 = gid - MQKV * CC;
        wob[g2] = f2bf(wo[g2]);
    }
    if (gid < MQKV)
        bqkv[gid] = (gid < 512) ? bq[gid] : ((gid < 1024) ? bk[gid - 512] : bv[gid - 1024]);
}

// ---------------- GroupNorm -> transposed bf16 hn_t[b][n][c] ----------------
__global__ __launch_bounds__(256) void groupnorm_t_kernel(
        const float* __restrict__ x, const float* __restrict__ gsc,
        const float* __restrict__ gbi, short* __restrict__ hnt) {
    const int b = blockIdx.x >> 5, g = blockIdx.x & 31;
    const int count = CPG * NSP;  // 16384
    const size_t base = ((size_t)b * CC + (size_t)g * CPG) * NSP;
    float s = 0.f, ss = 0.f;
    for (int i = threadIdx.x; i < count; i += 256) {
        float v = x[base + i];
        s += v; ss += v * v;
    }
    __shared__ float red[2][4];
    s = wave_reduce_sum(s); ss = wave_reduce_sum(ss);
    const int wid = threadIdx.x >> 6, lane = threadIdx.x & 63;
    if (lane == 0) { red[0][wid] = s; red[1][wid] = ss; }
    __syncthreads();
    if (threadIdx.x == 0) {
        float ts  = red[0][0] + red[0][1] + red[0][2] + red[0][3];
        float tss = red[1][0] + red[1][1] + red[1][2] + red[1][3];
        float mu = ts / count;
        float var = tss / count - mu * mu;
        red[0][0] = mu;
        red[1][0] = rsqrtf(var + GN_EPS);
    }
    __syncthreads();
    const float mu = red[0][0], rstd = red[1][0];
    float sc[16], bi[16];
    #pragma unroll
    for (int ci = 0; ci < 16; ++ci) {
        sc[ci] = gsc[g * CPG + ci] * rstd;
        bi[ci] = gbi[g * CPG + ci];
    }
    for (int n0 = 0; n0 < NSP; n0 += 256) {
        const int n = n0 + threadIdx.x;
        short tmp[16];
        #pragma unroll
        for (int ci = 0; ci < 16; ++ci) {
            float v = x[base + (size_t)ci * NSP + n];
            tmp[ci] = f2bf((v - mu) * sc[ci] + bi[ci]);
        }
        const size_t ob = ((size_t)b * NSP + n) * CC + g * CPG;
        *(bf16x8*)&hnt[ob]     = *(bf16x8*)&tmp[0];
        *(bf16x8*)&hnt[ob + 8] = *(bf16x8*)&tmp[8];
    }
}

// ---------------- bf16 MFMA GEMM: Y[b,o,n] = bias[o] + sum_k A[o,k] Bt[b,n,k] ----
// MODE 0: Y bf16 (QKV).  MODE 1: Y fp32 with residual (wo).
// grid: (64 = 8 ntile * 8 batch, M/128). block 256 = 4 waves, each 64x64.
template <int MODE>
__global__ __launch_bounds__(256) void gemm_bt_kernel(
        const short* __restrict__ A, const float* __restrict__ bias,
        const short* __restrict__ Bt, void* __restrict__ Yv,
        const float* __restrict__ res, int M) {
    __shared__ short As[128 * 64];
    __shared__ short Bs[128 * 64];
    const int nt = blockIdx.x;
    const int b = nt >> 3, n0 = (nt & 7) * 128;
    const int o0 = blockIdx.y * 128;
    const int t = threadIdx.x, w = t >> 6, lane = t & 63;
    const int quad = lane >> 4, l16 = lane & 15;
    const int wm = w & 1, wn = w >> 1;
    const int srow = lane >> 3, scol = (lane & 7) * 8;

    f32x4 acc[4][4];
    #pragma unroll
    for (int i = 0; i < 4; ++i)
        #pragma unroll
        for (int j = 0; j < 4; ++j) acc[i][j] = (f32x4){0.f, 0.f, 0.f, 0.f};

    const short* Ab = A + (size_t)o0 * 512;
    const short* Bb = Bt + ((size_t)b * 1024 + n0) * 512;

    for (int k0 = 0; k0 < 512; k0 += 64) {
        #pragma unroll
        for (int i = 0; i < 4; ++i) {
            const int r0 = w * 32 + i * 8;
            __builtin_amdgcn_global_load_lds(
                (glb_u32*)(Ab + (size_t)(r0 + srow) * 512 + k0 + scol),
                (lds_u32*)&As[r0 * 64], 16, 0, 0);
            __builtin_amdgcn_global_load_lds(
                (glb_u32*)(Bb + (size_t)(r0 + srow) * 512 + k0 + scol),
                (lds_u32*)&Bs[r0 * 64], 16, 0, 0);
        }
        __syncthreads();

        bf16x8 af[4][2], bfr[4][2];
        #pragma unroll
        for (int mi = 0; mi < 4; ++mi)
            #pragma unroll
            for (int s = 0; s < 2; ++s)
                af[mi][s] = *(bf16x8*)&As[(wm * 64 + mi * 16 + l16) * 64 + quad * 8 + s * 32];
        #pragma unroll
        for (int ni = 0; ni < 4; ++ni)
            #pragma unroll
            for (int s = 0; s < 2; ++s)
                bfr[ni][s] = *(bf16x8*)&Bs[(wn * 64 + ni * 16 + l16) * 64 + quad * 8 + s * 32];
        #pragma unroll
        for (int mi = 0; mi < 4; ++mi)
            #pragma unroll
            for (int ni = 0; ni < 4; ++ni)
                #pragma unroll
                for (int s = 0; s < 2; ++s)
                    acc[mi][ni] = __builtin_amdgcn_mfma_f32_16x16x32_bf16(
                        af[mi][s], bfr[ni][s], acc[mi][ni], 0, 0, 0);
        __syncthreads();
    }

    #pragma unroll
    for (int mi = 0; mi < 4; ++mi) {
        #pragma unroll
        for (int r = 0; r < 4; ++r) {
            const int m = wm * 64 + mi * 16 + quad * 4 + r;
            const float bv = bias[o0 + m];
            const size_t rowb = ((size_t)b * M + o0 + m) * 1024 + n0;
            if (MODE == 0) {
                short* Y = (short*)Yv;
                #pragma unroll
                for (int ni = 0; ni < 4; ++ni) {
                    const int n = wn * 64 + ni * 16 + l16;
                    Y[rowb + n] = f2bf(acc[mi][ni][r] + bv);
                }
            } else {
                float* Y = (float*)Yv;
                #pragma unroll
                for (int ni = 0; ni < 4; ++ni) {
                    const int n = wn * 64 + ni * 16 + l16;
                    Y[rowb + n] = acc[mi][ni][r] + bv + res[rowb + n];
                }
            }
        }
    }
}

// ---------------- flash attention, MFMA bf16, bf16 in/out ----------------
__global__ __launch_bounds__(256) void attn_mfma_kernel(
        const short* __restrict__ qkv, short* __restrict__ obt) {
    __shared__ short Ks[64][72];
    __shared__ short Vs[64][72];
    __shared__ short Ps[4][16][72];
    const int q0 = blockIdx.x * 64;
    const int h = blockIdx.y, b = blockIdx.z;
    const int t = threadIdx.x;
    const int w = t >> 6, lane = t & 63;
    const int quad = lane >> 4, l16 = lane & 15;
    const size_t qbase = ((size_t)b * MQKV + h * DH) * NSP;
    const size_t kbase = ((size_t)b * MQKV + 512 + h * DH) * NSP;
    const size_t vbase = ((size_t)b * MQKV + 1024 + h * DH) * NSP;
    const int qcol = q0 + w * 16 + l16;

    bf16x8 qf[2];
    #pragma unroll
    for (int s = 0; s < 2; ++s) {
        short tmp[8];
        #pragma unroll
        for (int j = 0; j < 8; ++j)
            tmp[j] = qkv[qbase + (size_t)(quad * 8 + j + 32 * s) * NSP + qcol];
        qf[s] = *(bf16x8*)tmp;
    }

    float mrun = -1e30f, lrun = 0.f;
    f32x4 oacc[4];
    #pragma unroll
    for (int i = 0; i < 4; ++i) oacc[i] = (f32x4){0.f, 0.f, 0.f, 0.f};
    const float scale = 0.125f;

    for (int k0 = 0; k0 < NSP; k0 += 64) {
        __syncthreads();
        #pragma unroll
        for (int p = 0; p < 2; ++p) {
            int idx = t + p * 256;
            int k = idx & 63, d8 = (idx >> 6) * 8;
            const short* src = qkv + kbase + (size_t)d8 * NSP + k0 + k;
            short tmp[8];
            #pragma unroll
            for (int j = 0; j < 8; ++j) tmp[j] = src[(size_t)j * NSP];
            *(bf16x8*)&Ks[k][d8] = *(bf16x8*)tmp;
        }
        #pragma unroll
        for (int p = 0; p < 2; ++p) {
            int idx = t + p * 256;
            int d = idx >> 3, k8 = (idx & 7) * 8;
            *(bf16x8*)&Vs[d][k8] =
                *(const bf16x8*)(qkv + vbase + (size_t)d * NSP + k0 + k8);
        }
        __syncthreads();

        f32x4 st[4];
        #pragma unroll
        for (int ks = 0; ks < 4; ++ks) {
            f32x4 a2 = (f32x4){0.f, 0.f, 0.f, 0.f};
            #pragma unroll
            for (int s = 0; s < 2; ++s) {
                bf16x8 ka = *(bf16x8*)&Ks[ks * 16 + l16][quad * 8 + 32 * s];
                a2 = __builtin_amdgcn_mfma_f32_16x16x32_bf16(ka, qf[s], a2, 0, 0, 0);
            }
            st[ks] = a2;
        }
        float tmax = -1e30f;
        #pragma unroll
        for (int ks = 0; ks < 4; ++ks)
            #pragma unroll
            for (int r = 0; r < 4; ++r) {
                st[ks][r] *= scale;
                tmax = fmaxf(tmax, st[ks][r]);
            }
        tmax = fmaxf(tmax, __shfl_xor(tmax, 16, 64));
        tmax = fmaxf(tmax, __shfl_xor(tmax, 32, 64));
        float mnew = fmaxf(mrun, tmax);
        float alpha = __expf(mrun - mnew);
        float psum = 0.f;
        short pb[16];
        #pragma unroll
        for (int ks = 0; ks < 4; ++ks)
            #pragma unroll
            for (int r = 0; r < 4; ++r) {
                float p = __expf(st[ks][r] - mnew);
                psum += p;
                pb[ks * 4 + r] = f2bf(p);
            }
        psum += __shfl_xor(psum, 16, 64);
        psum += __shfl_xor(psum, 32, 64);
        lrun = lrun * alpha + psum;
        mrun = mnew;
        #pragma unroll
        for (int i = 0; i < 4; ++i)
            #pragma unroll
            for (int r = 0; r < 4; ++r) oacc[i][r] *= alpha;

        #pragma unroll
        for (int ks = 0; ks < 4; ++ks)
            *(short4v*)&Ps[w][l16][ks * 16 + quad * 4] = *(short4v*)&pb[ks * 4];
        bf16x8 pf[2];
        #pragma unroll
        for (int s = 0; s < 2; ++s)
            pf[s] = *(bf16x8*)&Ps[w][l16][quad * 8 + 32 * s];

        #pragma unroll
        for (int ds = 0; ds < 4; ++ds)
            #pragma unroll
            for (int s = 0; s < 2; ++s) {
                bf16x8 va = *(bf16x8*)&Vs[ds * 16 + l16][quad * 8 + 32 * s];
                oacc[ds] = __builtin_amdgcn_mfma_f32_16x16x32_bf16(va, pf[s], oacc[ds], 0, 0, 0);
            }
    }

    const float inv = 1.0f / lrun;
    #pragma unroll
    for (int ds = 0; ds < 4; ++ds) {
        short o4[4];
        #pragma unroll
        for (int r = 0; r < 4; ++r) o4[r] = f2bf(oacc[ds][r] * inv);
        *(short4v*)&obt[((size_t)b * NSP + qcol) * CC + h * DH + ds * 16 + quad * 4] =
            *(short4v*)o4;
    }
}

extern "C" void kernel_launch(void* const* d_in, const int* in_sizes, int n_in,
                              void* d_out, int out_size, void* d_ws, size_t ws_size,
                              hipStream_t stream) {
    const float* x   = (const float*)d_in[0];
    const float* gsc = (const float*)d_in[1];
    const float* gbi = (const float*)d_in[2];
    const float* wq  = (const float*)d_in[3];
    const float* bq  = (const float*)d_in[4];
    const float* wk  = (const float*)d_in[5];
    const float* bk  = (const float*)d_in[6];
    const float* wv  = (const float*)d_in[7];
    const float* bv  = (const float*)d_in[8];
    const float* wo  = (const float*)d_in[9];
    const float* bo  = (const float*)d_in[10];
    float* out = (float*)d_out;

    short* wqkv_bf = (short*)d_ws;                       // 1536*512
    short* wo_bf   = wqkv_bf + (size_t)MQKV * CC;        // 512*512
    float* bqkv    = (float*)(wo_bf + (size_t)CC * CC);  // 1536
    short* hnt     = (short*)(bqkv + MQKV);              // 8*1024*512
    short* qkv     = hnt + (size_t)BB * NSP * CC;        // 8*1536*1024
    short* obt     = qkv + (size_t)BB * MQKV * NSP;      // 8*1024*512

    convert_w_kernel<<<(MQKV * CC + CC * CC) / 256, 256, 0, stream>>>(
        wq, wk, wv, wo, bq, bk, bv, wqkv_bf, wo_bf, bqkv);

    groupnorm_t_kernel<<<BB * NGROUPS, 256, 0, stream>>>(x, gsc, gbi, hnt);

    dim3 qkvgrid(64, MQKV / 128);
    gemm_bt_kernel<0><<<qkvgrid, 256, 0, stream>>>(
        wqkv_bf, bqkv, hnt, (void*)qkv, nullptr, MQKV);

    dim3 agrid(NSP / 64, HEADS, BB);
    attn_mfma_kernel<<<agrid, 256, 0, stream>>>(qkv, obt);

    dim3 wogrid(64, CC / 128);
    gemm_bt_kernel<1><<<wogrid, 256, 0, stream>>>(
        wo_bf, bo, obt, (void*)out, x, CC);
}